// Round 6
// baseline (300.568 us; speedup 1.0000x reference)
//
#include <hip/hip_runtime.h>
#include <math.h>

#define N      128
#define NSQ    (N * N)          // 16384
#define VOL    (N * N * N)      // 2097152
#define NSHELL 64
#define BTOT   8
#define FPI    3.14159265358979323846f

#define TP9    9                // k2 tile pitch in float2 (col stride 18 dwords -> near-free)

#if __has_builtin(__builtin_amdgcn_permlane32_swap) && __has_builtin(__builtin_amdgcn_permlane16_swap)
#define HAVE_PLSWAP 1
#else
#define HAVE_PLSWAP 0
#endif

typedef unsigned uint2v __attribute__((ext_vector_type(2)));

// ---------------------------------------------------------------------------
// Twiddles (verified r3-r5). c64/s64: exp(-i pi l/64) in-lane stage.
// c32/s32, c16/s16: raw all-lane for permlane pair stages. c8..e2,e1: role
// twiddles for DPP/swizzle stages.
// ---------------------------------------------------------------------------
struct TW {
    float c64, s64;
    float c32, s32, c16, s16;
#if !HAVE_PLSWAP
    float e32, e16;
#endif
    float c8, s8, e8;
    float c4, s4, e4;
    float c2, s2, e2;
    float e1;
};

__device__ inline void mk_tw(int l, TW& w) {
    __sincosf(-FPI * (float)l * (1.0f / 64.0f), &w.s64, &w.c64);
#if HAVE_PLSWAP
    __sincosf(-FPI * (float)(l & 31) * (1.0f / 32.0f), &w.s32, &w.c32);
    __sincosf(-FPI * (float)(l & 15) * (1.0f / 16.0f), &w.s16, &w.c16);
#else
    { float s, c; __sincosf(-FPI * (float)(l & 31) * (1.0f / 32.0f), &s, &c);
      const bool hi = (l & 32); w.c32 = hi ? c : 1.f; w.s32 = hi ? s : 0.f; w.e32 = hi ? -1.f : 1.f; }
    { float s, c; __sincosf(-FPI * (float)(l & 15) * (1.0f / 16.0f), &s, &c);
      const bool hi = (l & 16); w.c16 = hi ? c : 1.f; w.s16 = hi ? s : 0.f; w.e16 = hi ? -1.f : 1.f; }
#endif
    { float s, c; __sincosf(-FPI * (float)(l & 7) * (1.0f / 8.0f), &s, &c);
      const bool hi = (l & 8); w.c8 = hi ? c : 1.f; w.s8 = hi ? s : 0.f; w.e8 = hi ? -1.f : 1.f; }
    { float s, c; __sincosf(-FPI * (float)(l & 3) * (1.0f / 4.0f), &s, &c);
      const bool hi = (l & 4); w.c4 = hi ? c : 1.f; w.s4 = hi ? s : 0.f; w.e4 = hi ? -1.f : 1.f; }
    { float s, c; __sincosf(-FPI * (float)(l & 1) * (1.0f / 2.0f), &s, &c);
      const bool hi = (l & 2); w.c2 = hi ? c : 1.f; w.s2 = hi ? s : 0.f; w.e2 = hi ? -1.f : 1.f; }
    w.e1 = (l & 1) ? -1.f : 1.f;
}

// ---------------------------------------------------------------------------
// Cross-lane primitives (verified r4/r5).
// ---------------------------------------------------------------------------
template<int CTRL>
__device__ inline float2 xdpp(float2 v) {
    return make_float2(
        __int_as_float(__builtin_amdgcn_update_dpp(__float_as_int(v.x), __float_as_int(v.x), CTRL, 0xF, 0xF, false)),
        __int_as_float(__builtin_amdgcn_update_dpp(__float_as_int(v.y), __float_as_int(v.y), CTRL, 0xF, 0xF, false)));
}
__device__ inline float2 xswz4(float2 v) {   // xor4: BitMode (4<<10)|0x1F
    return make_float2(
        __int_as_float(__builtin_amdgcn_ds_swizzle(__float_as_int(v.x), 0x101F)),
        __int_as_float(__builtin_amdgcn_ds_swizzle(__float_as_int(v.y), 0x101F)));
}

__device__ inline float2 bfly(float2 v, float2 o, float c, float s, float e) {
    const float tx = fmaf(e, v.x, o.x), ty = fmaf(e, v.y, o.y);
    return make_float2(tx * c - ty * s, tx * s + ty * c);
}

__device__ inline void bf64(float2& v0, float2& v1, float c, float s) {
    const float dx = v0.x - v1.x, dy = v0.y - v1.y;
    v0.x += v1.x; v0.y += v1.y;
    v1.x = dx * c - dy * s;
    v1.y = dx * s + dy * c;
}

#if HAVE_PLSWAP
__device__ inline void swp32f(float& a, float& b) {
    uint2v r = __builtin_amdgcn_permlane32_swap(__float_as_uint(a), __float_as_uint(b), false, false);
    a = __uint_as_float(r[0]); b = __uint_as_float(r[1]);
}
__device__ inline void swp16f(float& a, float& b) {
    uint2v r = __builtin_amdgcn_permlane16_swap(__float_as_uint(a), __float_as_uint(b), false, false);
    a = __uint_as_float(r[0]); b = __uint_as_float(r[1]);
}
__device__ inline void pair32(float2& A, float2& B, float c, float s) {
    float P = A.x, Q = B.x, R = A.y, S = B.y;
    swp32f(P, Q); swp32f(R, S);
    const float sx = P + Q, sy = R + S;
    const float dx = P - Q, dy = R - S;
    float fx = dx * c - dy * s;
    float fy = dx * s + dy * c;
    float ax = sx, bx = fx, ay = sy, by = fy;
    swp32f(ax, bx); swp32f(ay, by);
    A = make_float2(ax, ay); B = make_float2(bx, by);
}
__device__ inline void pair16(float2& A, float2& B, float c, float s) {
    float P = A.x, Q = B.x, R = A.y, S = B.y;
    swp16f(P, Q); swp16f(R, S);
    const float sx = P + Q, sy = R + S;
    const float dx = P - Q, dy = R - S;
    float fx = dx * c - dy * s;
    float fy = dx * s + dy * c;
    float ax = sx, bx = fx, ay = sy, by = fy;
    swp16f(ax, bx); swp16f(ay, by);
    A = make_float2(ax, ay); B = make_float2(bx, by);
}
#else
__device__ inline float2 xshfl(float2 v, int m) {
    return make_float2(__shfl_xor(v.x, m), __shfl_xor(v.y, m));
}
#endif

// ---------------------------------------------------------------------------
// Two 128-point DIF FFTs computed together across one 64-lane wave (r4/r5).
// In: lane l holds elem l (v0), l+64 (v1). Out: bins 2*bitrev6(l), +1.
// ---------------------------------------------------------------------------
__device__ inline void fft128p(float2& a0, float2& a1, float2& b0, float2& b1,
                               const TW& w) {
    bf64(a0, a1, w.c64, w.s64);
    bf64(b0, b1, w.c64, w.s64);
#if HAVE_PLSWAP
    pair32(a0, b0, w.c32, w.s32);
    pair32(a1, b1, w.c32, w.s32);
    pair16(a0, b0, w.c16, w.s16);
    pair16(a1, b1, w.c16, w.s16);
#else
    { float2 o = xshfl(a0, 32); a0 = bfly(a0, o, w.c32, w.s32, w.e32); }
    { float2 o = xshfl(a1, 32); a1 = bfly(a1, o, w.c32, w.s32, w.e32); }
    { float2 o = xshfl(b0, 32); b0 = bfly(b0, o, w.c32, w.s32, w.e32); }
    { float2 o = xshfl(b1, 32); b1 = bfly(b1, o, w.c32, w.s32, w.e32); }
    { float2 o = xshfl(a0, 16); a0 = bfly(a0, o, w.c16, w.s16, w.e16); }
    { float2 o = xshfl(a1, 16); a1 = bfly(a1, o, w.c16, w.s16, w.e16); }
    { float2 o = xshfl(b0, 16); b0 = bfly(b0, o, w.c16, w.s16, w.e16); }
    { float2 o = xshfl(b1, 16); b1 = bfly(b1, o, w.c16, w.s16, w.e16); }
#endif
    { float2 o = xdpp<0x128>(a0); a0 = bfly(a0, o, w.c8, w.s8, w.e8); }
    { float2 o = xdpp<0x128>(a1); a1 = bfly(a1, o, w.c8, w.s8, w.e8); }
    { float2 o = xdpp<0x128>(b0); b0 = bfly(b0, o, w.c8, w.s8, w.e8); }
    { float2 o = xdpp<0x128>(b1); b1 = bfly(b1, o, w.c8, w.s8, w.e8); }
    { float2 o = xswz4(a0); a0 = bfly(a0, o, w.c4, w.s4, w.e4); }
    { float2 o = xswz4(a1); a1 = bfly(a1, o, w.c4, w.s4, w.e4); }
    { float2 o = xswz4(b0); b0 = bfly(b0, o, w.c4, w.s4, w.e4); }
    { float2 o = xswz4(b1); b1 = bfly(b1, o, w.c4, w.s4, w.e4); }
    { float2 o = xdpp<0x4E>(a0); a0 = bfly(a0, o, w.c2, w.s2, w.e2); }
    { float2 o = xdpp<0x4E>(a1); a1 = bfly(a1, o, w.c2, w.s2, w.e2); }
    { float2 o = xdpp<0x4E>(b0); b0 = bfly(b0, o, w.c2, w.s2, w.e2); }
    { float2 o = xdpp<0x4E>(b1); b1 = bfly(b1, o, w.c2, w.s2, w.e2); }
    { float2 o = xdpp<0xB1>(a0); a0.x = fmaf(w.e1, a0.x, o.x); a0.y = fmaf(w.e1, a0.y, o.y); }
    { float2 o = xdpp<0xB1>(a1); a1.x = fmaf(w.e1, a1.x, o.x); a1.y = fmaf(w.e1, a1.y, o.y); }
    { float2 o = xdpp<0xB1>(b0); b0.x = fmaf(w.e1, b0.x, o.x); b0.y = fmaf(w.e1, b0.y, o.y); }
    { float2 o = xdpp<0xB1>(b1); b1.x = fmaf(w.e1, b1.x, o.x); b1.y = fmaf(w.e1, b1.y, o.y); }
}

// slot <-> bin permutation (involution): bin(slot s) = 2*bitrev6(s>>1) + (s&1)
__device__ inline int binof(int s) {
    return (int)(((__brev((unsigned)(s >> 1)) >> 26) << 1) | (unsigned)(s & 1));
}

// ---------------------------------------------------------------------------
// Exact floor(sqrt(r2)) for integer r2.
// ---------------------------------------------------------------------------
__device__ inline int isqrt_i(int r2) {
    int s = (int)sqrtf((float)r2);
    s -= (s * s > r2);
    s += ((s + 1) * (s + 1) <= r2);
    return s;
}

// ---------------------------------------------------------------------------
// Pass 1 (fused z+y FFT), persistent over 4 x-planes with register prefetch.
// Block = (batch, x-group of 4). The 32 global loads for plane x+1 are issued
// BEFORE phase-1 FFT of plane x, so HBM latency hides under FFT + LDS store +
// phase-2 + global store of the current plane. LDS = 2 XOR-swizzled float2
// planes = 128 KiB (layout verified r3-r5).
// ---------------------------------------------------------------------------
__global__ __launch_bounds__(1024) void k_fft_zy(const float* __restrict__ ref,
                                                 const float* __restrict__ pred,
                                                 float2* __restrict__ Z, int b0) {
    __shared__ float2 P0[64 * 128];   // 65536 B
    __shared__ float2 P1[64 * 128];   // 65536 B
    const int t = threadIdx.x, l = t & 63, w = t >> 6;   // 16 waves
    const int xg = blockIdx.x & 31;
    const int bl = blockIdx.x >> 5;
    TW tw;
    mk_tw(l, tw);
    const int f2 = (int)(__brev((unsigned)l) >> 26) << 1;   // 2*bitrev6(l)
    const size_t inb = (size_t)(b0 + bl) * VOL;
    const size_t zbb = (size_t)bl * VOL;

#define LOADX(XV, A0, A1) {                                                   \
    const float* rp_ = ref  + inb + (size_t)(XV) * NSQ;                       \
    const float* pq_ = pred + inb + (size_t)(XV) * NSQ;                       \
    _Pragma("unroll")                                                         \
    for (int k_ = 0; k_ < 8; ++k_) {                                          \
        const int y_ = w * 8 + k_;                                            \
        A0[k_] = make_float2(rp_[y_ * N + l],      pq_[y_ * N + l]);          \
        A1[k_] = make_float2(rp_[y_ * N + l + 64], pq_[y_ * N + l + 64]);     \
    } }

    float2 V0[8], V1[8], W0[8], W1[8];
    LOADX(xg * 4, V0, V1);
#pragma unroll
    for (int i = 0; i < 4; ++i) {
        const int x = xg * 4 + i;
        if (i < 3) LOADX(x + 1, W0, W1);             // prefetch next plane
        // phase 1: z-FFT of 16 lines held in V
#pragma unroll
        for (int k = 0; k < 8; k += 2)
            fft128p(V0[k], V1[k], V0[k + 1], V1[k + 1], tw);
        const int row = l * 128, sw = l & 31;
#pragma unroll
        for (int k = 0; k < 8; ++k) {
            const int c = (w * 8 + k) ^ sw;          // lane l holds slots 2l,2l+1
            P0[row + c] = V0[k];
            P1[row + c] = V1[k];
        }
        __syncthreads();
        // phase 2: y-FFT per z-slot column, straight to global
        float2 U0[8], U1[8];
#pragma unroll
        for (int k = 0; k < 8; ++k) {
            const int s = w * 8 + k, j = s >> 1;
            const float2* PP = (s & 1) ? P1 : P0;
            const int c = l ^ (j & 31);
            U0[k] = PP[j * 128 + c];
            U1[k] = PP[j * 128 + c + 64];
        }
#pragma unroll
        for (int k = 0; k < 8; k += 2)
            fft128p(U0[k], U1[k], U0[k + 1], U1[k + 1], tw);
        const size_t zb = zbb + (size_t)x * NSQ;
#pragma unroll
        for (int k = 0; k < 8; ++k) {
            const int s = w * 8 + k;
            *reinterpret_cast<float4*>(&Z[zb + (size_t)s * N + f2]) =
                make_float4(U0[k].x, U0[k].y, U1[k].x, U1[k].y);
        }
        __syncthreads();                             // plane reuse barrier
        if (i < 3) {
#pragma unroll
            for (int k = 0; k < 8; ++k) { V0[k] = W0[k]; V1[k] = W1[k]; }
        }
    }
#undef LOADX
}

// ---------------------------------------------------------------------------
// Pass 2 (fused x-FFT + Hermitian shell reduce), half-space in kz (verified
// r3-r5), now persistent + double-buffered. Block = (batch, fz-slot q,
// parity g). Tile j covers yc = g? 15-j : j (min|fy| = 8j+g); nt tiles valid.
// Pipeline per tile: issue next tile's global loads to regs -> ds_write
// current regs to buf[cur] -> ONE barrier -> compute from buf[cur] while
// next loads fly. Bins accumulate in LDS across tiles; one global flush.
// LDS 2x18KB + bins ~= 40KB -> 4 blocks/CU, 16 waves.
// ---------------------------------------------------------------------------
__global__ __launch_bounds__(256) void k_fftx_reduce(const float2* __restrict__ Z,
                                                     float* __restrict__ accum, int b0) {
    const int t = threadIdx.x, l = t & 63, w = t >> 6;   // 4 waves
    const int g  = blockIdx.x & 1;
    const int q  = (blockIdx.x >> 1) & 63;
    const int bl = blockIdx.x >> 7;

    const int zs  = ((q >> 1) << 2) | (q & 1);   // slots whose bin is in [0,64)
    const int fz  = binof(zs);                   // fz in [0,63]
    const int fzz = fz * fz;
    const int M   = isqrt_i(4095 - fzz);         // max |fy| with fzz+fy^2 < 4096
    const int nt  = ((M - g) >> 3) + 1;          // valid tiles (M >= 11 > g always)

    __shared__ float2 TA[2][128 * TP9];          // 2 x 9216 B
    __shared__ float2 TB[2][128 * TP9];          // 2 x 9216 B
    __shared__ float bins[4 * 193];              // 3088 B

    const int mzs = binof((N - fz) & (N - 1));   // slot holding bin -fz (fz=0 -> zs)
    const size_t zbase = (size_t)bl * VOL;
    const float2* ZA = Z + zbase + (size_t)zs  * N;
    const float2* ZB = Z + zbase + (size_t)mzs * N;
    const int lxx = t >> 3, lyi = t & 7;         // load mapping: 64B segments per 8 lanes

    for (int i = t; i < 4 * 193; i += 256) bins[i] = 0.f;

    TW tw;
    mk_tw(l, tw);
    const int B6 = (int)(__brev((unsigned)l) >> 26);
    const int f2 = B6 << 1;
    const int p0 = (int)(__brev((unsigned)((64 - B6) & 63)) >> 26);
    const int p1 = 63 - l;
    const int fx0 = f2 - ((f2 >= 64) ? N : 0);
    const int fx0s = fx0 * fx0;
    const int fx1s = (fx0 + 1) * (fx0 + 1);

#define LOADT(J, RA, RB) {                                                    \
    const int yc_ = g ? (15 - (J)) : (J);                                     \
    const int y_  = yc_ * 8 + lyi;                                            \
    const int my_ = (N - y_) & (N - 1);                                       \
    _Pragma("unroll")                                                         \
    for (int qq_ = 0; qq_ < 4; ++qq_) {                                       \
        const int xr_ = lxx + 32 * qq_;                                       \
        RA[qq_] = ZA[(size_t)xr_ * NSQ + y_];                                 \
        RB[qq_] = ZB[(size_t)xr_ * NSQ + my_];                                \
    } }

#define FLUSH(CS, C, P1V, P2V)                                                \
    if ((unsigned)(CS) < (unsigned)NSHELL) {                                  \
        atomicAdd(&mybins[(CS) * 3 + 0], (C));                                \
        atomicAdd(&mybins[(CS) * 3 + 1], (P1V));                              \
        atomicAdd(&mybins[(CS) * 3 + 2], (P2V));                              \
    }

    float* mybins = bins + (t & 3) * 193;
    float2 Ra[4], Rb[4], Sa[4], Sb[4];
    LOADT(0, Ra, Rb);
    int cur = 0;
    for (int j = 0; j < nt; ++j) {
        if (j + 1 < nt) LOADT(j + 1, Sa, Sb);    // issue next tile's loads early
#pragma unroll
        for (int qq = 0; qq < 4; ++qq) {         // stage current tile to LDS
            const int xr = lxx + 32 * qq;
            TA[cur][xr * TP9 + lyi] = Ra[qq];
            TB[cur][xr * TP9 + lyi] = Rb[qq];
        }
        __syncthreads();                         // one barrier per tile

        const int yc  = g ? (15 - j) : j;
        const int y0  = yc * 8;
        const int yv0 = y0 + w * 2;              // wave's 2 consecutive y's
        const int fy0 = yv0 - ((yv0 >= 64) ? N : 0);
        const int fy1 = (yv0 + 1) - (((yv0 + 1) >= 64) ? N : 0);
        const int r2yz[2] = { fy0 * fy0 + fzz, fy1 * fy1 + fzz };
        if (r2yz[0] < 4096 || r2yz[1] < 4096) {  // wave-uniform
            float2 A0[2], A1[2], M0[2], M1[2];
#pragma unroll
            for (int k = 0; k < 2; ++k) {
                const int yi = w * 2 + k;
                A0[k] = TA[cur][l * TP9 + yi];
                A1[k] = TA[cur][(l + 64) * TP9 + yi];
                M0[k] = TB[cur][l * TP9 + yi];
                M1[k] = TB[cur][(l + 64) * TP9 + yi];
            }
            fft128p(A0[0], A1[0], M0[0], M1[0], tw);
            fft128p(A0[1], A1[1], M0[1], M1[1], tw);
            float rC0 = 0.f, rP10 = 0.f, rP20 = 0.f; int cs0 = -1;
            float rC1 = 0.f, rP11 = 0.f, rP21 = 0.f; int cs1 = -1;
#pragma unroll
            for (int k = 0; k < 2; ++k) {
                const float Bx0 = __shfl(M0[k].x, p0), By0 = __shfl(M0[k].y, p0);
                const float Bx1 = __shfl(M1[k].x, p1), By1 = __shfl(M1[k].y, p1);
                const int s0 = isqrt_i(fx0s + r2yz[k]);
                if (s0 != cs0) { FLUSH(cs0, rC0, rP10, rP20); cs0 = s0; rC0 = rP10 = rP20 = 0.f; }
                if (s0 < NSHELL) {
                    const float F1x = 0.5f * (A0[k].x + Bx0);
                    const float F1y = 0.5f * (A0[k].y - By0);
                    const float F2x = 0.5f * (A0[k].y + By0);
                    const float F2y = 0.5f * (Bx0 - A0[k].x);
                    rC0  += F1x * F2x + F1y * F2y;
                    rP10 += F1x * F1x + F1y * F1y;
                    rP20 += F2x * F2x + F2y * F2y;
                }
                const int s1 = isqrt_i(fx1s + r2yz[k]);
                if (s1 != cs1) { FLUSH(cs1, rC1, rP11, rP21); cs1 = s1; rC1 = rP11 = rP21 = 0.f; }
                if (s1 < NSHELL) {
                    const float F1x = 0.5f * (A1[k].x + Bx1);
                    const float F1y = 0.5f * (A1[k].y - By1);
                    const float F2x = 0.5f * (A1[k].y + By1);
                    const float F2y = 0.5f * (Bx1 - A1[k].x);
                    rC1  += F1x * F2x + F1y * F2y;
                    rP11 += F1x * F1x + F1y * F1y;
                    rP21 += F2x * F2x + F2y * F2y;
                }
            }
            FLUSH(cs0, rC0, rP10, rP20);
            FLUSH(cs1, rC1, rP11, rP21);
        }
        if (j + 1 < nt) {
#pragma unroll
            for (int qq = 0; qq < 4; ++qq) { Ra[qq] = Sa[qq]; Rb[qq] = Sb[qq]; }
        }
        cur ^= 1;
    }
#undef FLUSH
#undef LOADT
    __syncthreads();

    const float wsc = (fz == 0) ? 1.f : 2.f;     // -fz plane contributes equally (exact)
    const int smin = isqrt_i(fzz + g * g);       // lowest shell this block touches
    float* acc = accum + (size_t)(b0 + bl) * (NSHELL * 3);
    for (int i = smin * 3 + t; i < NSHELL * 3; i += 256) {
        const float v = bins[i] + bins[193 + i] + bins[2 * 193 + i] + bins[3 * 193 + i];
        atomicAdd(&acc[i], v * wsc);
    }
}

// ---------------------------------------------------------------------------
// Pass 3: FSC + loss. 512 threads = 8 batches x 64 shells.
// ---------------------------------------------------------------------------
__global__ __launch_bounds__(512) void k_final(const float* __restrict__ accum,
                                               float* __restrict__ out) {
    __shared__ float red[8];
    const int tid = threadIdx.x;
    const float* a = accum + (size_t)tid * 3;
    const float fsc = a[0] / (sqrtf(a[1] * a[2]) + 1e-8f);
    float v = fsc * fsc;
#pragma unroll
    for (int off = 32; off > 0; off >>= 1) v += __shfl_down(v, off);
    if ((tid & 63) == 0) red[tid >> 6] = v;
    __syncthreads();
    if (tid == 0) {
        float ssum = 0.f;
#pragma unroll
        for (int i = 0; i < 8; ++i) ssum += red[i];
        out[0] = 1.0f - ssum / 512.0f;
    }
}

extern "C" void kernel_launch(void* const* d_in, const int* in_sizes, int n_in,
                              void* d_out, int out_size, void* d_ws, size_t ws_size,
                              hipStream_t stream) {
    const float* ref  = (const float*)d_in[0];
    const float* pred = (const float*)d_in[1];
    float* out = (float*)d_out;

    char*   ws    = (char*)d_ws;
    float*  accum = (float*)ws;
    float2* Zbuf  = (float2*)(ws + 8192);

    const size_t zbytes = (size_t)VOL * sizeof(float2);
    int cap = 1;
    if (ws_size > 8192) {
        size_t c = (ws_size - 8192) / zbytes;
        cap = (c < 1) ? 1 : (c > BTOT ? BTOT : (int)c);
    }

    hipMemsetAsync(accum, 0, BTOT * NSHELL * 3 * sizeof(float), stream);

    for (int b0 = 0; b0 < BTOT; b0 += cap) {
        const int nb = (BTOT - b0 < cap) ? (BTOT - b0) : cap;
        k_fft_zy<<<nb * 32, 1024, 0, stream>>>(ref, pred, Zbuf, b0);
        k_fftx_reduce<<<nb * 128, 256, 0, stream>>>(Zbuf, accum, b0);
    }
    k_final<<<1, 512, 0, stream>>>(accum, out);
}